// Round 11
// baseline (1185.099 us; speedup 1.0000x reference)
//
#include <hip/hip_runtime.h>

#define NCH 256
#define DWS 2752   // padded per-instance dynamic-weight stride (64B aligned)

static __device__ __forceinline__ float fsig(float x){ return __builtin_amdgcn_rcpf(1.f + __expf(-x)); }
static __device__ __forceinline__ float fsilu(float x){ return x * __builtin_amdgcn_rcpf(1.f + __expf(-x)); }

// ---------------- fused weight transposes (lat 256x512, ml 256x256) -------
__global__ void transpose2_k(const float* __restrict__ lat_w, float* __restrict__ latwT,
                             const float* __restrict__ ml_w,  float* __restrict__ mlwT){
  int i = blockIdx.x*256 + threadIdx.x;
  if (i < 131072){ int r = i >> 9, c = i & 511; latwT[c*256 + r] = lat_w[i]; }
  else { int j = i - 131072; int r = j >> 8, c = j & 255; mlwT[c*256 + r] = ml_w[j]; }
}

// ---------------- level-5 lateral: feats[(b*256+p)*256+d] ----------------
__global__ void __launch_bounds__(256) lat5_k(const float* __restrict__ x5, const float* __restrict__ latwT,
                       const float* __restrict__ lat_b, float* __restrict__ feats){
  int b  = blockIdx.x >> 6;
  int p0 = (blockIdx.x & 63) * 4;
  int t  = threadIdx.x;
  int tl = t & 63, pg = t >> 6;       // pg = pixel 0..3, tl*4 = channel quad
  __shared__ float xs[4][512];
  for (int s=t; s<2048; s+=256){ int c=s>>2, px=s&3; xs[px][c] = x5[(b*512+c)*256 + p0+px]; }
  __syncthreads();
  float a0=0.f,a1=0.f,a2=0.f,a3=0.f;
  const float* xrow = xs[pg];
  for (int c=0;c<512;++c){
    float xv = xrow[c];
    float4 wv = *(const float4*)(latwT + c*256 + tl*4);
    a0 += xv*wv.x; a1 += xv*wv.y; a2 += xv*wv.z; a3 += xv*wv.w;
  }
  float4 bb = *(const float4*)(lat_b + tl*4);
  float4 o; o.x=a0+bb.x; o.y=a1+bb.y; o.z=a2+bb.z; o.w=a3+bb.w;
  *(float4*)(feats + (size_t)(b*256 + p0+pg)*256 + tl*4) = o;
}

// ---------------- 4-layer MLP core (Linear->LN->SiLU x4), result in acc ----
__device__ __forceinline__ void mlp_core(const float* __restrict__ X, const int* __restrict__ srcrow,
                             const float* __restrict__ W, const float* __restrict__ B,
                             const float* __restrict__ G, const float* __restrict__ Bt,
                             int row0, float xs[16][NCH], float acc[4][4]){
  int t = threadIdx.x;
  int wv = t >> 6, lane = t & 63;
  for (int rr=0;rr<4;++rr){
    int row = row0+rr;
    int src = srcrow ? srcrow[row] : row;
    #pragma unroll
    for (int q=0;q<4;++q) xs[wv*4+rr][q*64+lane] = X[(size_t)src*NCH + q*64+lane];
  }
  for (int l=0;l<4;++l){
    const float* Wl = W + l*NCH*NCH;
    float4 bb = *(const float4*)(B + l*NCH + lane*4);
    #pragma unroll
    for (int rr=0;rr<4;++rr){ acc[rr][0]=bb.x; acc[rr][1]=bb.y; acc[rr][2]=bb.z; acc[rr][3]=bb.w; }
    for (int c=0;c<NCH;++c){
      float4 w4 = *(const float4*)(Wl + c*NCH + lane*4);
      #pragma unroll
      for (int rr=0;rr<4;++rr){
        float xv = xs[wv*4+rr][c];
        acc[rr][0] += xv*w4.x; acc[rr][1] += xv*w4.y; acc[rr][2] += xv*w4.z; acc[rr][3] += xv*w4.w;
      }
    }
    float4 gg = *(const float4*)(G  + l*NCH + lane*4);
    float4 bt = *(const float4*)(Bt + l*NCH + lane*4);
    #pragma unroll
    for (int rr=0;rr<4;++rr){
      float s  = acc[rr][0]+acc[rr][1]+acc[rr][2]+acc[rr][3];
      float s2 = acc[rr][0]*acc[rr][0]+acc[rr][1]*acc[rr][1]+acc[rr][2]*acc[rr][2]+acc[rr][3]*acc[rr][3];
      #pragma unroll
      for (int o=32;o>0;o>>=1){ s += __shfl_xor(s,o); s2 += __shfl_xor(s2,o); }
      float m = s*(1.f/256.f);
      float rstd = __builtin_amdgcn_rsqf(s2*(1.f/256.f) - m*m + 1e-5f);
      float z0 = fsilu((acc[rr][0]-m)*rstd*gg.x + bt.x);
      float z1 = fsilu((acc[rr][1]-m)*rstd*gg.y + bt.y);
      float z2 = fsilu((acc[rr][2]-m)*rstd*gg.z + bt.z);
      float z3 = fsilu((acc[rr][3]-m)*rstd*gg.w + bt.w);
      acc[rr][0]=z0; acc[rr][1]=z1; acc[rr][2]=z2; acc[rr][3]=z3;
      *(float4*)(&xs[wv*4+rr][lane*4]) = make_float4(z0,z1,z2,z3);
    }
  }
}

// loc branch: MLP + fused dout=1 head -> logits (no hidden round-trip)
__global__ void __launch_bounds__(256) mlp_loc_k(const float* __restrict__ X,
                             const float* __restrict__ W, const float* __restrict__ B,
                             const float* __restrict__ G, const float* __restrict__ Bt,
                             const float* __restrict__ Wout, const float* __restrict__ Bout,
                             float* __restrict__ logits){
  __shared__ float xs[16][NCH];
  float acc[4][4];
  int t = threadIdx.x, wv = t>>6, lane = t&63;
  int row0 = blockIdx.x*16 + wv*4;
  mlp_core(X, nullptr, W, B, G, Bt, row0, xs, acc);
  float4 wo = *(const float4*)(Wout + lane*4);
  float b0 = Bout[0];
  #pragma unroll
  for (int rr=0;rr<4;++rr){
    float p = acc[rr][0]*wo.x + acc[rr][1]*wo.y + acc[rr][2]*wo.z + acc[rr][3]*wo.w;
    #pragma unroll
    for (int o=32;o>0;o>>=1) p += __shfl_xor(p,o);
    if (lane==0) logits[row0+rr] = p + b0;
  }
}

// duo: blocks 0..24 = ker MLP (writes H for big head); 25..49 = pre MLP with
// fused 17-wide presence head (sigmoid), no hidden round-trip.
__global__ void __launch_bounds__(256) mlp_duo_k(const float* __restrict__ X, const int* __restrict__ srcrow,
                             const float* __restrict__ W1, const float* __restrict__ B1,
                             const float* __restrict__ G1, const float* __restrict__ Bt1, float* __restrict__ H1,
                             const float* __restrict__ W2, const float* __restrict__ B2,
                             const float* __restrict__ G2, const float* __restrict__ Bt2,
                             const float* __restrict__ preWo, const float* __restrict__ preBo,
                             float* __restrict__ presence){
  __shared__ float xs[16][NCH];
  float acc[4][4];
  int t = threadIdx.x, wv = t>>6, lane = t&63;
  int blk = blockIdx.x;
  if (blk < 25){
    int row0 = blk*16 + wv*4;
    mlp_core(X, srcrow, W1, B1, G1, Bt1, row0, xs, acc);
    #pragma unroll
    for (int rr=0;rr<4;++rr)
      *(float4*)(H1 + (size_t)(row0+rr)*NCH + lane*4) = make_float4(acc[rr][0],acc[rr][1],acc[rr][2],acc[rr][3]);
  } else {
    int row0 = (blk-25)*16 + wv*4;
    mlp_core(X, srcrow, W2, B2, G2, Bt2, row0, xs, acc);
    int c0 = lane*4;
    #pragma unroll
    for (int rr=0;rr<4;++rr){
      for (int k=0;k<17;++k){
        float p = acc[rr][0]*preWo[(c0+0)*17+k] + acc[rr][1]*preWo[(c0+1)*17+k]
                + acc[rr][2]*preWo[(c0+2)*17+k] + acc[rr][3]*preWo[(c0+3)*17+k];
        #pragma unroll
        for (int o=32;o>0;o>>=1) p += __shfl_xor(p,o);
        if (lane==0) presence[(size_t)(row0+rr)*17 + k] = fsig(p + preBo[k]);
      }
    }
  }
}

// ---------------- final linear (ker 2737-wide head) ----
__global__ void __launch_bounds__(256) linear_out_k(const float* __restrict__ H, const float* __restrict__ Wout,
                             const float* __restrict__ Bout, float* __restrict__ out,
                             int dout, int ostride, int sig, int jt){
  int bid = blockIdx.x;
  int rt = bid / jt, jtile = bid - rt*jt;
  int j0 = jtile*256;
  int t = threadIdx.x;
  int ty = t>>6, tx = t&63;
  __shared__ float xs[16][NCH];
  for (int s=t; s<16*NCH; s+=256){ int r=s>>8, c=s&255; xs[r][c]=H[(size_t)(rt*16+r)*NCH+c]; }
  __syncthreads();
  int jbase = j0 + tx*4;
  int jok[4]; float bo[4];
  #pragma unroll
  for (int jj=0;jj<4;++jj){ jok[jj] = (jbase+jj < dout); bo[jj] = jok[jj] ? Bout[jbase+jj] : 0.f; }
  float o[4][4];
  #pragma unroll
  for (int rr=0;rr<4;++rr){ o[rr][0]=bo[0]; o[rr][1]=bo[1]; o[rr][2]=bo[2]; o[rr][3]=bo[3]; }
  for (int c=0;c<NCH;++c){
    float w0 = jok[0] ? Wout[(size_t)c*dout + jbase+0] : 0.f;
    float w1 = jok[1] ? Wout[(size_t)c*dout + jbase+1] : 0.f;
    float w2 = jok[2] ? Wout[(size_t)c*dout + jbase+2] : 0.f;
    float w3 = jok[3] ? Wout[(size_t)c*dout + jbase+3] : 0.f;
    #pragma unroll
    for (int rr=0;rr<4;++rr){
      float xv = xs[ty*4+rr][c];
      o[rr][0]+=xv*w0; o[rr][1]+=xv*w1; o[rr][2]+=xv*w2; o[rr][3]+=xv*w3;
    }
  }
  #pragma unroll
  for (int rr=0;rr<4;++rr)
    #pragma unroll
    for (int jj=0;jj<4;++jj)
      if (jok[jj]){
        float v = o[rr][jj];
        if (sig) v = fsig(v);
        out[(size_t)(rt*16+ty*4+rr)*ostride + jbase+jj] = v;
      }
}

// ---------------- top-k (exact JAX ordering via rank counting) ------------
__global__ void topk_k(const float* __restrict__ logits, float* __restrict__ out_scores,
                       float* __restrict__ out_ninst, int* __restrict__ srcrow,
                       float* __restrict__ mask_off){
  int b = blockIdx.x, t = threadIdx.x;
  __shared__ float v[256];
  __shared__ int cnt;
  v[t] = logits[b*256+t];
  if (t==0) cnt=0;
  __syncthreads();
  float mv = v[t];
  int rank = 0;
  for (int j=0;j<256;++j){
    float u = v[j];
    rank += (u > mv) || (u == mv && j < t);
  }
  if (rank < 100){
    out_scores[b*100 + rank] = fsig(mv);
    srcrow[b*100 + rank] = b*256 + t;
    mask_off[(b*100+rank)*2+0] = ((t & 15) + 0.5f)*(1.f/16.f);
    mask_off[(b*100+rank)*2+1] = ((t >> 4) + 0.5f)*(1.f/16.f);
    if (mv > 0.f) atomicAdd(&cnt, 1);
  }
  __syncthreads();
  if (t==0) out_ninst[b] = (float)cnt;
}

// ---------------- x3 lateral: mfl[b][d][p] (channel-planar) ----------------
__global__ void __launch_bounds__(256) masklat_k(const float* __restrict__ x3, const float* __restrict__ mlwT,
                          const float* __restrict__ ml_b, float* __restrict__ mfl){
  int b  = blockIdx.x >> 6;
  int p0 = (blockIdx.x & 63) * 64;
  int t  = threadIdx.x;
  int tl = t & 63, pg = t >> 6;         // channels tl*4..+3, pixels pg*16..+15
  __shared__ float xs[16][64];
  float acc[4][16];
  #pragma unroll
  for (int dd=0;dd<4;++dd)
    #pragma unroll
    for (int r=0;r<16;++r) acc[dd][r]=0.f;
  for (int c0=0;c0<256;c0+=16){
    __syncthreads();
    for (int s=t; s<1024; s+=256){ int cc=s>>6, pp=s&63; xs[cc][pp] = x3[(size_t)(b*256 + c0+cc)*4096 + p0+pp]; }
    __syncthreads();
    #pragma unroll
    for (int cc=0;cc<16;++cc){
      float4 w4 = *(const float4*)(mlwT + (c0+cc)*256 + tl*4);
      #pragma unroll
      for (int r4=0;r4<4;++r4){
        float4 xv = *(const float4*)(&xs[cc][pg*16 + r4*4]);
        acc[0][r4*4+0]+=xv.x*w4.x; acc[0][r4*4+1]+=xv.y*w4.x; acc[0][r4*4+2]+=xv.z*w4.x; acc[0][r4*4+3]+=xv.w*w4.x;
        acc[1][r4*4+0]+=xv.x*w4.y; acc[1][r4*4+1]+=xv.y*w4.y; acc[1][r4*4+2]+=xv.z*w4.y; acc[1][r4*4+3]+=xv.w*w4.y;
        acc[2][r4*4+0]+=xv.x*w4.z; acc[2][r4*4+1]+=xv.y*w4.z; acc[2][r4*4+2]+=xv.z*w4.z; acc[2][r4*4+3]+=xv.w*w4.z;
        acc[3][r4*4+0]+=xv.x*w4.w; acc[3][r4*4+1]+=xv.y*w4.w; acc[3][r4*4+2]+=xv.z*w4.w; acc[3][r4*4+3]+=xv.w*w4.w;
      }
    }
  }
  float4 bb = *(const float4*)(ml_b + tl*4);
  float bias[4] = {bb.x, bb.y, bb.z, bb.w};
  #pragma unroll
  for (int dd=0;dd<4;++dd){
    float* base = mfl + (size_t)(b*256 + tl*4+dd)*4096 + p0 + pg*16;
    #pragma unroll
    for (int r4=0;r4<4;++r4)
      *(float4*)(base + r4*4) = make_float4(acc[dd][r4*4+0]+bias[dd], acc[dd][r4*4+1]+bias[dd],
                                            acc[dd][r4*4+2]+bias[dd], acc[dd][r4*4+3]+bias[dd]);
  }
}

// ---------------- 3x3 conv (SAME), c split into 4 groups -> partial --------
__global__ void __launch_bounds__(256) conv3x3_k(const float* __restrict__ mfl, const float* __restrict__ mh_w,
                          float* __restrict__ partial){
  int bid = blockIdx.x;
  int g = bid & 3, tile = (bid>>2) & 15, b = bid >> 6;
  int ty0 = (tile>>2)*16, tx0 = (tile&3)*16;
  int t = threadIdx.x;
  int dg = t >> 6;                   // 8 channels dg*8..+7
  int pb = t & 63; int pby = pb >> 3, pbx = pb & 7;
  int py = pby*2, px = pbx*2;
  __shared__ float hal[18*18];
  __shared__ float wl[288];
  float acc[8][4];
  #pragma unroll
  for (int dd=0;dd<8;++dd){ acc[dd][0]=0.f; acc[dd][1]=0.f; acc[dd][2]=0.f; acc[dd][3]=0.f; }
  for (int c = g*64; c < (g+1)*64; ++c){
    __syncthreads();
    for (int s=t; s<324; s+=256){
      int hy = s/18, hx = s - hy*18;
      int gy = ty0+hy-1, gx = tx0+hx-1;
      float vv = 0.f;
      if ((unsigned)gy < 64u && (unsigned)gx < 64u) vv = mfl[(size_t)(b*256+c)*4096 + gy*64+gx];
      hal[s] = vv;
    }
    for (int s=t; s<288; s+=256){ int d=s/9, tap=s-d*9; wl[s] = mh_w[(size_t)(d*256+c)*9 + tap]; }
    __syncthreads();
    float nb[4][4];
    #pragma unroll
    for (int i=0;i<4;++i)
      #pragma unroll
      for (int j=0;j<4;++j) nb[i][j] = hal[(py+i)*18 + (px+j)];
    #pragma unroll
    for (int dd=0;dd<8;++dd){
      int d = dg*8+dd;
      #pragma unroll
      for (int ky=0;ky<3;++ky)
        #pragma unroll
        for (int kx=0;kx<3;++kx){
          float wv = wl[d*9 + ky*3+kx];
          acc[dd][0] += nb[ky+0][kx+0]*wv;
          acc[dd][1] += nb[ky+0][kx+1]*wv;
          acc[dd][2] += nb[ky+1][kx+0]*wv;
          acc[dd][3] += nb[ky+1][kx+1]*wv;
        }
    }
  }
  #pragma unroll
  for (int dd=0;dd<8;++dd){
    int d = dg*8+dd;
    float* pp = partial + ((size_t)(g*4+b)*32 + d)*4096;
    pp[(ty0+py  )*64 + tx0+px  ] = acc[dd][0];
    pp[(ty0+py  )*64 + tx0+px+1] = acc[dd][1];
    pp[(ty0+py+1)*64 + tx0+px  ] = acc[dd][2];
    pp[(ty0+py+1)*64 + tx0+px+1] = acc[dd][3];
  }
}

__global__ void convepi_k(const float* __restrict__ partial, const float* __restrict__ mh_b,
                          float* __restrict__ mf){
  int i = blockIdx.x*256 + threadIdx.x;      // 4*32*4096
  int p = i & 4095; int d = (i>>12) & 31; int b = i >> 17;
  float s = mh_b[d];
  #pragma unroll
  for (int g=0; g<4; ++g) s += partial[((size_t)(g*4+b)*32 + d)*4096 + p];
  mf[i] = fsilu(s);
}

// ---------------- dynamic per-instance convs + partial argmax --------------
// 3 sub-blocks per instance (chks {0-2,3-5,6-7}) for CU load balance;
// launch_bounds(256,2) (VGPR cap 256, fits 240) enables 2 blocks/CU so the
// per-CU LDS pipe (the bottleneck) stays fed. Partial argmax -> ws; merged
// by dynmerge_k.
__global__ void __launch_bounds__(256,2) dyn_k(const float* __restrict__ mf, const float* __restrict__ dw,
                      const float* __restrict__ mask_off, float* __restrict__ subv, int* __restrict__ subi){
  int bid = blockIdx.x;
  int inst = bid / 3, sub = bid - inst*3;
  int b = inst / 100;
  int t = threadIdx.x;
  __shared__ __align__(16) float Ws[2176];   // w1[34][32] | b1[32] | w2[32][32] | b2[32]
  __shared__ __align__(16) float W3p[640];   // [c(32)][k(20)] padded
  __shared__ __align__(16) float B3p[20];
  __shared__ float offsh[2];
  const float* src = dw + (size_t)inst*DWS;
  for (int s=t; s<2176; s+=256) Ws[s] = src[s];
  for (int s=t; s<640; s+=256){ int c=s/20, k=s-c*20; W3p[s] = (k<17) ? src[2176 + c*17 + k] : 0.f; }
  if (t<20) B3p[t] = (t<17) ? src[2720+t] : 0.f;
  if (t<2) offsh[t] = mask_off[inst*2+t];
  __syncthreads();
  float offx = offsh[0], offy = offsh[1];
  float bestv[17]; int besti[17];
  #pragma unroll
  for (int k=0;k<17;++k){ bestv[k] = -3.4e38f; besti[k]=0; }
  const float* mfb = mf + (size_t)b*32*4096;
  int cBeg = sub*3, cEnd = (sub==2) ? 8 : sub*3+3;
  #pragma unroll 1
  for (int chk=cBeg; chk<cEnd; ++chk){
    int pa = chk*512 + t;
    int pb = pa + 256;
    float xa[32], xb[32];
    #pragma unroll
    for (int c=0;c<32;++c){
      const float* mp = mfb + c*4096;
      xa[c] = mp[pa]; xb[c] = mp[pb];
    }
    float gxa = ((pa & 63) + 0.5f)*(1.f/64.f) - offx;
    float gya = ((pa >> 6) + 0.5f)*(1.f/64.f) - offy;
    float gxb = ((pb & 63) + 0.5f)*(1.f/64.f) - offx;
    float gyb = ((pb >> 6) + 0.5f)*(1.f/64.f) - offy;
    float ya[32], yb[32];
    // -------- layer 1 --------
    #pragma unroll
    for (int dq=0; dq<8; ++dq){
      float4 bb = *(const float4*)(Ws + 1088 + dq*4);
      float4 wx = *(const float4*)(Ws + 32*32 + dq*4);
      float4 wy = *(const float4*)(Ws + 33*32 + dq*4);
      float4 aa, ab;
      aa.x = bb.x + gxa*wx.x + gya*wy.x; aa.y = bb.y + gxa*wx.y + gya*wy.y;
      aa.z = bb.z + gxa*wx.z + gya*wy.z; aa.w = bb.w + gxa*wx.w + gya*wy.w;
      ab.x = bb.x + gxb*wx.x + gyb*wy.x; ab.y = bb.y + gxb*wx.y + gyb*wy.y;
      ab.z = bb.z + gxb*wx.z + gyb*wy.z; ab.w = bb.w + gxb*wx.w + gyb*wy.w;
      float4 w[4];
      #pragma unroll
      for (int j=0;j<4;++j) w[j] = *(const float4*)(Ws + j*32 + dq*4);
      #pragma unroll
      for (int c=0;c<32;++c){
        float4 wc = w[c&3];
        if (c < 28) w[c&3] = *(const float4*)(Ws + (c+4)*32 + dq*4);
        aa.x += xa[c]*wc.x; aa.y += xa[c]*wc.y; aa.z += xa[c]*wc.z; aa.w += xa[c]*wc.w;
        ab.x += xb[c]*wc.x; ab.y += xb[c]*wc.y; ab.z += xb[c]*wc.z; ab.w += xb[c]*wc.w;
      }
      __builtin_amdgcn_sched_barrier(0);
      ya[dq*4+0]=fsilu(aa.x); ya[dq*4+1]=fsilu(aa.y); ya[dq*4+2]=fsilu(aa.z); ya[dq*4+3]=fsilu(aa.w);
      yb[dq*4+0]=fsilu(ab.x); yb[dq*4+1]=fsilu(ab.y); yb[dq*4+2]=fsilu(ab.z); yb[dq*4+3]=fsilu(ab.w);
    }
    // -------- layer 2 (h overwrites xa/xb; x dead) --------
    #pragma unroll
    for (int dq=0; dq<8; ++dq){
      float4 bb = *(const float4*)(Ws + 2144 + dq*4);
      float4 aa = bb, ab = bb;
      float4 w[4];
      #pragma unroll
      for (int j=0;j<4;++j) w[j] = *(const float4*)(Ws + 1120 + j*32 + dq*4);
      #pragma unroll
      for (int c=0;c<32;++c){
        float4 wc = w[c&3];
        if (c < 28) w[c&3] = *(const float4*)(Ws + 1120 + (c+4)*32 + dq*4);
        aa.x += ya[c]*wc.x; aa.y += ya[c]*wc.y; aa.z += ya[c]*wc.z; aa.w += ya[c]*wc.w;
        ab.x += yb[c]*wc.x; ab.y += yb[c]*wc.y; ab.z += yb[c]*wc.z; ab.w += yb[c]*wc.w;
      }
      __builtin_amdgcn_sched_barrier(0);
      xa[dq*4+0]=fsilu(aa.x); xa[dq*4+1]=fsilu(aa.y); xa[dq*4+2]=fsilu(aa.z); xa[dq*4+3]=fsilu(aa.w);
      xb[dq*4+0]=fsilu(ab.x); xb[dq*4+1]=fsilu(ab.y); xb[dq*4+2]=fsilu(ab.z); xb[dq*4+3]=fsilu(ab.w);
    }
    // -------- layer 3 + argmax --------
    #pragma unroll
    for (int kq=0; kq<5; ++kq){
      float4 aa = *(const float4*)(B3p + kq*4);
      float4 ab = aa;
      float4 w[4];
      #pragma unroll
      for (int j=0;j<4;++j) w[j] = *(const float4*)(W3p + j*20 + kq*4);
      #pragma unroll
      for (int c=0;c<32;++c){
        float4 wc = w[c&3];
        if (c < 28) w[c&3] = *(const float4*)(W3p + (c+4)*20 + kq*4);
        aa.x += xa[c]*wc.x; aa.y += xa[c]*wc.y; aa.z += xa[c]*wc.z; aa.w += xa[c]*wc.w;
        ab.x += xb[c]*wc.x; ab.y += xb[c]*wc.y; ab.z += xb[c]*wc.z; ab.w += xb[c]*wc.w;
      }
      __builtin_amdgcn_sched_barrier(0);
      int k0 = kq*4;
      if (k0+0 < 17){ if (aa.x > bestv[k0+0]){ bestv[k0+0]=aa.x; besti[k0+0]=pa; }
                      if (ab.x > bestv[k0+0]){ bestv[k0+0]=ab.x; besti[k0+0]=pb; } }
      if (k0+1 < 17){ if (aa.y > bestv[k0+1]){ bestv[k0+1]=aa.y; besti[k0+1]=pa; }
                      if (ab.y > bestv[k0+1]){ bestv[k0+1]=ab.y; besti[k0+1]=pb; } }
      if (k0+2 < 17){ if (aa.z > bestv[k0+2]){ bestv[k0+2]=aa.z; besti[k0+2]=pa; }
                      if (ab.z > bestv[k0+2]){ bestv[k0+2]=ab.z; besti[k0+2]=pb; } }
      if (k0+3 < 17){ if (aa.w > bestv[k0+3]){ bestv[k0+3]=aa.w; besti[k0+3]=pa; }
                      if (ab.w > bestv[k0+3]){ bestv[k0+3]=ab.w; besti[k0+3]=pb; } }
    }
  }
  // wave-level reduce, then one LDS pass over 4 wave leaders -> sub result
  __shared__ float rv[4][17];
  __shared__ int   ri[4][17];
  int lane = t & 63, wv = t >> 6;
  #pragma unroll
  for (int k=0;k<17;++k){
    float v = bestv[k]; int ix = besti[k];
    #pragma unroll
    for (int o=32;o>0;o>>=1){
      float v2 = __shfl_xor(v,o); int i2 = __shfl_xor(ix,o);
      if (v2 > v || (v2 == v && i2 < ix)){ v=v2; ix=i2; }
    }
    if (lane==0){ rv[wv][k]=v; ri[wv][k]=ix; }
  }
  __syncthreads();
  if (t < 17){
    float v = rv[0][t]; int ix = ri[0][t];
    #pragma unroll
    for (int w2=1;w2<4;++w2){
      float v2 = rv[w2][t]; int i2 = ri[w2][t];
      if (v2 > v || (v2 == v && i2 < ix)){ v=v2; ix=i2; }
    }
    subv[(size_t)bid*17 + t] = v;
    subi[(size_t)bid*17 + t] = ix;
  }
}

// merge 3 sub-results per instance -> keypoints
__global__ void dynmerge_k(const float* __restrict__ subv, const int* __restrict__ subi,
                           float* __restrict__ kp){
  int inst = blockIdx.x, t = threadIdx.x;
  if (t < 17){
    float v = subv[(size_t)(inst*3+0)*17 + t]; int ix = subi[(size_t)(inst*3+0)*17 + t];
    #pragma unroll
    for (int s=1;s<3;++s){
      float v2 = subv[(size_t)(inst*3+s)*17 + t]; int i2 = subi[(size_t)(inst*3+s)*17 + t];
      if (v2 > v || (v2 == v && i2 < ix)){ v=v2; ix=i2; }
    }
    kp[((size_t)inst*17+t)*2+0] = ((ix & 63)+0.5f)*8.f;
    kp[((size_t)inst*17+t)*2+1] = ((ix >> 6)+0.5f)*8.f;
  }
}

extern "C" void kernel_launch(void* const* d_in, const int* in_sizes, int n_in,
                              void* d_out, int out_size, void* d_ws, size_t ws_size,
                              hipStream_t stream){
  (void)in_sizes; (void)n_in; (void)out_size; (void)ws_size;
  const float* x3      = (const float*)d_in[1];
  const float* x5      = (const float*)d_in[2];
  const float* lat_w   = (const float*)d_in[3];
  const float* lat_b   = (const float*)d_in[4];
  const float* ml_w    = (const float*)d_in[5];
  const float* ml_b    = (const float*)d_in[6];
  const float* mh_w    = (const float*)d_in[7];
  const float* mh_b    = (const float*)d_in[8];
  const float* loc_w   = (const float*)d_in[9];
  const float* loc_b   = (const float*)d_in[10];
  const float* loc_g   = (const float*)d_in[11];
  const float* loc_bt  = (const float*)d_in[12];
  const float* loc_wo  = (const float*)d_in[13];
  const float* loc_bo  = (const float*)d_in[14];
  const float* pre_w   = (const float*)d_in[15];
  const float* pre_b   = (const float*)d_in[16];
  const float* pre_g   = (const float*)d_in[17];
  const float* pre_bt  = (const float*)d_in[18];
  const float* pre_wo  = (const float*)d_in[19];
  const float* pre_bo  = (const float*)d_in[20];
  const float* ker_w   = (const float*)d_in[21];
  const float* ker_b   = (const float*)d_in[22];
  const float* ker_g   = (const float*)d_in[23];
  const float* ker_bt  = (const float*)d_in[24];
  const float* ker_wo  = (const float*)d_in[25];
  const float* ker_bo  = (const float*)d_in[26];

  float* ws = (float*)d_ws;
  float* latwT     = ws;                  // 131072
  float* mlwT      = ws + 131072;         // 65536
  float* feats     = ws + 196608;         // 262144
  float* subv      = ws + 458752;         // 1200*17 = 20400
  int*   subi      = (int*)(ws + 479152); // 20400
  float* loc_logit = ws + 720896;         // 1024
  int*   srcrow    = (int*)(ws + 721920); // 512
  float* moff      = ws + 722432;         // 1024
  float* ker_h     = ws + 723456;         // 102400
  float* dwb       = ws + 928256;         // 400*2752 = 1100800
  float* mfl       = ws + 2029056;        // 4194304
  float* partialb  = ws + 6223360;        // 2097152
  float* mfb       = ws + 8320512;        // 524288   (end 8844800 floats ~35.4MB)

  float* out          = (float*)d_out;
  float* out_ninst    = out;
  float* out_scores   = out + 4;
  float* out_presence = out + 404;
  float* out_kp       = out + 7204;

  transpose2_k<<<768, 256, 0, stream>>>(lat_w, latwT, ml_w, mlwT);
  lat5_k<<<256, 256, 0, stream>>>(x5, latwT, lat_b, feats);
  mlp_loc_k<<<64, 256, 0, stream>>>(feats, loc_w, loc_b, loc_g, loc_bt, loc_wo, loc_bo, loc_logit);
  topk_k<<<4, 256, 0, stream>>>(loc_logit, out_scores, out_ninst, srcrow, moff);
  mlp_duo_k<<<50, 256, 0, stream>>>(feats, srcrow,
                                    ker_w, ker_b, ker_g, ker_bt, ker_h,
                                    pre_w, pre_b, pre_g, pre_bt, pre_wo, pre_bo, out_presence);
  linear_out_k<<<275, 256, 0, stream>>>(ker_h, ker_wo, ker_bo, dwb, 2737, DWS, 0, 11);
  masklat_k<<<256, 256, 0, stream>>>(x3, mlwT, ml_b, mfl);
  conv3x3_k<<<256, 256, 0, stream>>>(mfl, mh_w, partialb);
  convepi_k<<<2048, 256, 0, stream>>>(partialb, mh_b, mfb);
  dyn_k<<<1200, 256, 0, stream>>>(mfb, dwb, moff, subv, subi);
  dynmerge_k<<<400, 64, 0, stream>>>(subv, subi, out_kp);
}

// Round 12
// 892.620 us; speedup vs baseline: 1.3277x; 1.3277x over previous
//
#include <hip/hip_runtime.h>

#define NCH 256
#define DWS 2752   // padded per-instance dynamic-weight stride (64B aligned)

static __device__ __forceinline__ float fsig(float x){ return __builtin_amdgcn_rcpf(1.f + __expf(-x)); }
static __device__ __forceinline__ float fsilu(float x){ return x * __builtin_amdgcn_rcpf(1.f + __expf(-x)); }

// ---------------- fused weight transposes (lat 256x512, ml 256x256) -------
__global__ void transpose2_k(const float* __restrict__ lat_w, float* __restrict__ latwT,
                             const float* __restrict__ ml_w,  float* __restrict__ mlwT){
  int i = blockIdx.x*256 + threadIdx.x;
  if (i < 131072){ int r = i >> 9, c = i & 511; latwT[c*256 + r] = lat_w[i]; }
  else { int j = i - 131072; int r = j >> 8, c = j & 255; mlwT[c*256 + r] = ml_w[j]; }
}

// ---------------- 4-layer MLP core (Linear->LN->SiLU x4), result in acc ----
__device__ __forceinline__ void mlp_core(const float* __restrict__ X, const int* __restrict__ srcrow,
                             const float* __restrict__ W, const float* __restrict__ B,
                             const float* __restrict__ G, const float* __restrict__ Bt,
                             int row0, float xs[16][NCH], float acc[4][4]){
  int t = threadIdx.x;
  int wv = t >> 6, lane = t & 63;
  for (int rr=0;rr<4;++rr){
    int row = row0+rr;
    int src = srcrow ? srcrow[row] : row;
    #pragma unroll
    for (int q=0;q<4;++q) xs[wv*4+rr][q*64+lane] = X[(size_t)src*NCH + q*64+lane];
  }
  for (int l=0;l<4;++l){
    const float* Wl = W + l*NCH*NCH;
    float4 bb = *(const float4*)(B + l*NCH + lane*4);
    #pragma unroll
    for (int rr=0;rr<4;++rr){ acc[rr][0]=bb.x; acc[rr][1]=bb.y; acc[rr][2]=bb.z; acc[rr][3]=bb.w; }
    for (int c=0;c<NCH;++c){
      float4 w4 = *(const float4*)(Wl + c*NCH + lane*4);
      #pragma unroll
      for (int rr=0;rr<4;++rr){
        float xv = xs[wv*4+rr][c];
        acc[rr][0] += xv*w4.x; acc[rr][1] += xv*w4.y; acc[rr][2] += xv*w4.z; acc[rr][3] += xv*w4.w;
      }
    }
    float4 gg = *(const float4*)(G  + l*NCH + lane*4);
    float4 bt = *(const float4*)(Bt + l*NCH + lane*4);
    #pragma unroll
    for (int rr=0;rr<4;++rr){
      float s  = acc[rr][0]+acc[rr][1]+acc[rr][2]+acc[rr][3];
      float s2 = acc[rr][0]*acc[rr][0]+acc[rr][1]*acc[rr][1]+acc[rr][2]*acc[rr][2]+acc[rr][3]*acc[rr][3];
      #pragma unroll
      for (int o=32;o>0;o>>=1){ s += __shfl_xor(s,o); s2 += __shfl_xor(s2,o); }
      float m = s*(1.f/256.f);
      float rstd = __builtin_amdgcn_rsqf(s2*(1.f/256.f) - m*m + 1e-5f);
      float z0 = fsilu((acc[rr][0]-m)*rstd*gg.x + bt.x);
      float z1 = fsilu((acc[rr][1]-m)*rstd*gg.y + bt.y);
      float z2 = fsilu((acc[rr][2]-m)*rstd*gg.z + bt.z);
      float z3 = fsilu((acc[rr][3]-m)*rstd*gg.w + bt.w);
      acc[rr][0]=z0; acc[rr][1]=z1; acc[rr][2]=z2; acc[rr][3]=z3;
      *(float4*)(&xs[wv*4+rr][lane*4]) = make_float4(z0,z1,z2,z3);
    }
  }
}

// ---------------- merged L1: lat5 (blocks 0..255) | masklat (256..511) -----
__global__ void __launch_bounds__(256) lat_mask_k(
    const float* __restrict__ x5, const float* __restrict__ latwT,
    const float* __restrict__ lat_b, float* __restrict__ feats,
    const float* __restrict__ x3, const float* __restrict__ mlwT,
    const float* __restrict__ ml_b, float* __restrict__ mfl){
  __shared__ float s5[4][512];
  __shared__ float s3[16][64];
  int t = threadIdx.x;
  if (blockIdx.x < 256){
    int bid = blockIdx.x;
    int b  = bid >> 6;
    int p0 = (bid & 63) * 4;
    int tl = t & 63, pg = t >> 6;
    for (int s=t; s<2048; s+=256){ int c=s>>2, px=s&3; s5[px][c] = x5[(b*512+c)*256 + p0+px]; }
    __syncthreads();
    float a0=0.f,a1=0.f,a2=0.f,a3=0.f;
    const float* xrow = s5[pg];
    for (int c=0;c<512;++c){
      float xv = xrow[c];
      float4 wv = *(const float4*)(latwT + c*256 + tl*4);
      a0 += xv*wv.x; a1 += xv*wv.y; a2 += xv*wv.z; a3 += xv*wv.w;
    }
    float4 bb = *(const float4*)(lat_b + tl*4);
    float4 o; o.x=a0+bb.x; o.y=a1+bb.y; o.z=a2+bb.z; o.w=a3+bb.w;
    *(float4*)(feats + (size_t)(b*256 + p0+pg)*256 + tl*4) = o;
  } else {
    int bid = blockIdx.x - 256;
    int b  = bid >> 6;
    int p0 = (bid & 63) * 64;
    int tl = t & 63, pg = t >> 6;
    float acc[4][16];
    #pragma unroll
    for (int dd=0;dd<4;++dd)
      #pragma unroll
      for (int r=0;r<16;++r) acc[dd][r]=0.f;
    for (int c0=0;c0<256;c0+=16){
      __syncthreads();
      for (int s=t; s<1024; s+=256){ int cc=s>>6, pp=s&63; s3[cc][pp] = x3[(size_t)(b*256 + c0+cc)*4096 + p0+pp]; }
      __syncthreads();
      #pragma unroll
      for (int cc=0;cc<16;++cc){
        float4 w4 = *(const float4*)(mlwT + (c0+cc)*256 + tl*4);
        #pragma unroll
        for (int r4=0;r4<4;++r4){
          float4 xv = *(const float4*)(&s3[cc][pg*16 + r4*4]);
          acc[0][r4*4+0]+=xv.x*w4.x; acc[0][r4*4+1]+=xv.y*w4.x; acc[0][r4*4+2]+=xv.z*w4.x; acc[0][r4*4+3]+=xv.w*w4.x;
          acc[1][r4*4+0]+=xv.x*w4.y; acc[1][r4*4+1]+=xv.y*w4.y; acc[1][r4*4+2]+=xv.z*w4.y; acc[1][r4*4+3]+=xv.w*w4.y;
          acc[2][r4*4+0]+=xv.x*w4.z; acc[2][r4*4+1]+=xv.y*w4.z; acc[2][r4*4+2]+=xv.z*w4.z; acc[2][r4*4+3]+=xv.w*w4.z;
          acc[3][r4*4+0]+=xv.x*w4.w; acc[3][r4*4+1]+=xv.y*w4.w; acc[3][r4*4+2]+=xv.z*w4.w; acc[3][r4*4+3]+=xv.w*w4.w;
        }
      }
    }
    float4 bb = *(const float4*)(ml_b + tl*4);
    float bias[4] = {bb.x, bb.y, bb.z, bb.w};
    #pragma unroll
    for (int dd=0;dd<4;++dd){
      float* base = mfl + (size_t)(b*256 + tl*4+dd)*4096 + p0 + pg*16;
      #pragma unroll
      for (int r4=0;r4<4;++r4)
        *(float4*)(base + r4*4) = make_float4(acc[dd][r4*4+0]+bias[dd], acc[dd][r4*4+1]+bias[dd],
                                              acc[dd][r4*4+2]+bias[dd], acc[dd][r4*4+3]+bias[dd]);
    }
  }
}

// ---------------- merged L2: mlp_loc (0..63) | conv3x3 (64..319) -----------
__global__ void __launch_bounds__(256) loc_conv_k(
    const float* __restrict__ feats,
    const float* __restrict__ loc_w, const float* __restrict__ loc_b,
    const float* __restrict__ loc_g, const float* __restrict__ loc_bt,
    const float* __restrict__ loc_wo, const float* __restrict__ loc_bo,
    float* __restrict__ logits,
    const float* __restrict__ mfl, const float* __restrict__ mh_w,
    float* __restrict__ partial){
  __shared__ float xs[16][NCH];
  __shared__ float hal[18*18];
  __shared__ float wl[288];
  int t = threadIdx.x;
  if (blockIdx.x < 64){
    float acc[4][4];
    int wv = t>>6, lane = t&63;
    int row0 = blockIdx.x*16 + wv*4;
    mlp_core(feats, nullptr, loc_w, loc_b, loc_g, loc_bt, row0, xs, acc);
    float4 wo = *(const float4*)(loc_wo + lane*4);
    float b0 = loc_bo[0];
    #pragma unroll
    for (int rr=0;rr<4;++rr){
      float p = acc[rr][0]*wo.x + acc[rr][1]*wo.y + acc[rr][2]*wo.z + acc[rr][3]*wo.w;
      #pragma unroll
      for (int o=32;o>0;o>>=1) p += __shfl_xor(p,o);
      if (lane==0) logits[row0+rr] = p + b0;
    }
  } else {
    int bid = blockIdx.x - 64;
    int g = bid & 3, tile = (bid>>2) & 15, b = bid >> 6;
    int ty0 = (tile>>2)*16, tx0 = (tile&3)*16;
    int dg = t >> 6;
    int pb = t & 63; int pby = pb >> 3, pbx = pb & 7;
    int py = pby*2, px = pbx*2;
    float acc[8][4];
    #pragma unroll
    for (int dd=0;dd<8;++dd){ acc[dd][0]=0.f; acc[dd][1]=0.f; acc[dd][2]=0.f; acc[dd][3]=0.f; }
    for (int c = g*64; c < (g+1)*64; ++c){
      __syncthreads();
      for (int s=t; s<324; s+=256){
        int hy = s/18, hx = s - hy*18;
        int gy = ty0+hy-1, gx = tx0+hx-1;
        float vv = 0.f;
        if ((unsigned)gy < 64u && (unsigned)gx < 64u) vv = mfl[(size_t)(b*256+c)*4096 + gy*64+gx];
        hal[s] = vv;
      }
      for (int s=t; s<288; s+=256){ int d=s/9, tap=s-d*9; wl[s] = mh_w[(size_t)(d*256+c)*9 + tap]; }
      __syncthreads();
      float nb[4][4];
      #pragma unroll
      for (int i=0;i<4;++i)
        #pragma unroll
        for (int j=0;j<4;++j) nb[i][j] = hal[(py+i)*18 + (px+j)];
      #pragma unroll
      for (int dd=0;dd<8;++dd){
        int d = dg*8+dd;
        #pragma unroll
        for (int ky=0;ky<3;++ky)
          #pragma unroll
          for (int kx=0;kx<3;++kx){
            float wv = wl[d*9 + ky*3+kx];
            acc[dd][0] += nb[ky+0][kx+0]*wv;
            acc[dd][1] += nb[ky+0][kx+1]*wv;
            acc[dd][2] += nb[ky+1][kx+0]*wv;
            acc[dd][3] += nb[ky+1][kx+1]*wv;
          }
      }
    }
    #pragma unroll
    for (int dd=0;dd<8;++dd){
      int d = dg*8+dd;
      float* pp = partial + ((size_t)(g*4+b)*32 + d)*4096;
      pp[(ty0+py  )*64 + tx0+px  ] = acc[dd][0];
      pp[(ty0+py  )*64 + tx0+px+1] = acc[dd][1];
      pp[(ty0+py+1)*64 + tx0+px  ] = acc[dd][2];
      pp[(ty0+py+1)*64 + tx0+px+1] = acc[dd][3];
    }
  }
}

// ---------------- merged L3: topk (0..3) | convepi (4..2051) ---------------
__global__ void topk_epi_k(const float* __restrict__ logits, float* __restrict__ out_scores,
                           float* __restrict__ out_ninst, int* __restrict__ srcrow,
                           float* __restrict__ mask_off,
                           const float* __restrict__ partial, const float* __restrict__ mh_b,
                           float* __restrict__ mf){
  __shared__ float v[256];
  __shared__ int cnt;
  int t = threadIdx.x;
  if (blockIdx.x < 4){
    int b = blockIdx.x;
    v[t] = logits[b*256+t];
    if (t==0) cnt=0;
    __syncthreads();
    float mv = v[t];
    int rank = 0;
    for (int j=0;j<256;++j){
      float u = v[j];
      rank += (u > mv) || (u == mv && j < t);
    }
    if (rank < 100){
      out_scores[b*100 + rank] = fsig(mv);
      srcrow[b*100 + rank] = b*256 + t;
      mask_off[(b*100+rank)*2+0] = ((t & 15) + 0.5f)*(1.f/16.f);
      mask_off[(b*100+rank)*2+1] = ((t >> 4) + 0.5f)*(1.f/16.f);
      if (mv > 0.f) atomicAdd(&cnt, 1);
    }
    __syncthreads();
    if (t==0) out_ninst[b] = (float)cnt;
  } else {
    int i = (blockIdx.x-4)*256 + t;      // 4*32*4096
    int p = i & 4095; int d = (i>>12) & 31; int b = i >> 17;
    float s = mh_b[d];
    #pragma unroll
    for (int g=0; g<4; ++g) s += partial[((size_t)(g*4+b)*32 + d)*4096 + p];
    mf[i] = fsilu(s);
  }
}

// duo: blocks 0..24 = ker MLP (writes H); 25..49 = pre MLP + presence head
__global__ void __launch_bounds__(256) mlp_duo_k(const float* __restrict__ X, const int* __restrict__ srcrow,
                             const float* __restrict__ W1, const float* __restrict__ B1,
                             const float* __restrict__ G1, const float* __restrict__ Bt1, float* __restrict__ H1,
                             const float* __restrict__ W2, const float* __restrict__ B2,
                             const float* __restrict__ G2, const float* __restrict__ Bt2,
                             const float* __restrict__ preWo, const float* __restrict__ preBo,
                             float* __restrict__ presence){
  __shared__ float xs[16][NCH];
  float acc[4][4];
  int t = threadIdx.x, wv = t>>6, lane = t&63;
  int blk = blockIdx.x;
  if (blk < 25){
    int row0 = blk*16 + wv*4;
    mlp_core(X, srcrow, W1, B1, G1, Bt1, row0, xs, acc);
    #pragma unroll
    for (int rr=0;rr<4;++rr)
      *(float4*)(H1 + (size_t)(row0+rr)*NCH + lane*4) = make_float4(acc[rr][0],acc[rr][1],acc[rr][2],acc[rr][3]);
  } else {
    int row0 = (blk-25)*16 + wv*4;
    mlp_core(X, srcrow, W2, B2, G2, Bt2, row0, xs, acc);
    int c0 = lane*4;
    #pragma unroll
    for (int rr=0;rr<4;++rr){
      for (int k=0;k<17;++k){
        float p = acc[rr][0]*preWo[(c0+0)*17+k] + acc[rr][1]*preWo[(c0+1)*17+k]
                + acc[rr][2]*preWo[(c0+2)*17+k] + acc[rr][3]*preWo[(c0+3)*17+k];
        #pragma unroll
        for (int o=32;o>0;o>>=1) p += __shfl_xor(p,o);
        if (lane==0) presence[(size_t)(row0+rr)*17 + k] = fsig(p + preBo[k]);
      }
    }
  }
}

// ---------------- final linear (ker 2737-wide head) ----
__global__ void __launch_bounds__(256) linear_out_k(const float* __restrict__ H, const float* __restrict__ Wout,
                             const float* __restrict__ Bout, float* __restrict__ out,
                             int dout, int ostride, int sig, int jt){
  int bid = blockIdx.x;
  int rt = bid / jt, jtile = bid - rt*jt;
  int j0 = jtile*256;
  int t = threadIdx.x;
  int ty = t>>6, tx = t&63;
  __shared__ float xs[16][NCH];
  for (int s=t; s<16*NCH; s+=256){ int r=s>>8, c=s&255; xs[r][c]=H[(size_t)(rt*16+r)*NCH+c]; }
  __syncthreads();
  int jbase = j0 + tx*4;
  int jok[4]; float bo[4];
  #pragma unroll
  for (int jj=0;jj<4;++jj){ jok[jj] = (jbase+jj < dout); bo[jj] = jok[jj] ? Bout[jbase+jj] : 0.f; }
  float o[4][4];
  #pragma unroll
  for (int rr=0;rr<4;++rr){ o[rr][0]=bo[0]; o[rr][1]=bo[1]; o[rr][2]=bo[2]; o[rr][3]=bo[3]; }
  for (int c=0;c<NCH;++c){
    float w0 = jok[0] ? Wout[(size_t)c*dout + jbase+0] : 0.f;
    float w1 = jok[1] ? Wout[(size_t)c*dout + jbase+1] : 0.f;
    float w2 = jok[2] ? Wout[(size_t)c*dout + jbase+2] : 0.f;
    float w3 = jok[3] ? Wout[(size_t)c*dout + jbase+3] : 0.f;
    #pragma unroll
    for (int rr=0;rr<4;++rr){
      float xv = xs[ty*4+rr][c];
      o[rr][0]+=xv*w0; o[rr][1]+=xv*w1; o[rr][2]+=xv*w2; o[rr][3]+=xv*w3;
    }
  }
  #pragma unroll
  for (int rr=0;rr<4;++rr)
    #pragma unroll
    for (int jj=0;jj<4;++jj)
      if (jok[jj]){
        float v = o[rr][jj];
        if (sig) v = fsig(v);
        out[(size_t)(rt*16+ty*4+rr)*ostride + jbase+jj] = v;
      }
}

// ---------------- dynamic per-instance convs + argmax ----------------------
// 2 px/thread; weights via LDS broadcast b128. 8-deep rotating prefetch:
// slot reuse after ~8x16 cyc >= ~120 cyc LDS latency -> no per-slot stall
// (r10's 4-deep stalled ~56 cyc per reuse). WAR dep still bounds in-flight
// reads (<= ~11) so no r6-style spill; (256,1) keeps VGPR cap at 512.
__global__ void __launch_bounds__(256,1) dyn_k(const float* __restrict__ mf, const float* __restrict__ dw,
                      const float* __restrict__ mask_off, float* __restrict__ kp){
  int inst = blockIdx.x;
  int b = inst / 100;
  int t = threadIdx.x;
  __shared__ __align__(16) float Ws[2176];   // w1[34][32] | b1[32] | w2[32][32] | b2[32]
  __shared__ __align__(16) float W3p[640];   // [c(32)][k(20)] padded
  __shared__ __align__(16) float B3p[20];
  __shared__ float offsh[2];
  const float* src = dw + (size_t)inst*DWS;
  for (int s=t; s<2176; s+=256) Ws[s] = src[s];
  for (int s=t; s<640; s+=256){ int c=s/20, k=s-c*20; W3p[s] = (k<17) ? src[2176 + c*17 + k] : 0.f; }
  if (t<20) B3p[t] = (t<17) ? src[2720+t] : 0.f;
  if (t<2) offsh[t] = mask_off[inst*2+t];
  __syncthreads();
  float offx = offsh[0], offy = offsh[1];
  float bestv[17]; int besti[17];
  #pragma unroll
  for (int k=0;k<17;++k){ bestv[k] = -3.4e38f; besti[k]=0; }
  const float* mfb = mf + (size_t)b*32*4096;
  #pragma unroll 1
  for (int chk=0; chk<8; ++chk){
    int pa = chk*512 + t;
    int pb = pa + 256;
    float xa[32], xb[32];
    #pragma unroll
    for (int c=0;c<32;++c){
      const float* mp = mfb + c*4096;
      xa[c] = mp[pa]; xb[c] = mp[pb];
    }
    float gxa = ((pa & 63) + 0.5f)*(1.f/64.f) - offx;
    float gya = ((pa >> 6) + 0.5f)*(1.f/64.f) - offy;
    float gxb = ((pb & 63) + 0.5f)*(1.f/64.f) - offx;
    float gyb = ((pb >> 6) + 0.5f)*(1.f/64.f) - offy;
    float ya[32], yb[32];
    // -------- layer 1 --------
    #pragma unroll
    for (int dq=0; dq<8; ++dq){
      float4 bb = *(const float4*)(Ws + 1088 + dq*4);
      float4 wx = *(const float4*)(Ws + 32*32 + dq*4);
      float4 wy = *(const float4*)(Ws + 33*32 + dq*4);
      float4 aa, ab;
      aa.x = bb.x + gxa*wx.x + gya*wy.x; aa.y = bb.y + gxa*wx.y + gya*wy.y;
      aa.z = bb.z + gxa*wx.z + gya*wy.z; aa.w = bb.w + gxa*wx.w + gya*wy.w;
      ab.x = bb.x + gxb*wx.x + gyb*wy.x; ab.y = bb.y + gxb*wx.y + gyb*wy.y;
      ab.z = bb.z + gxb*wx.z + gyb*wy.z; ab.w = bb.w + gxb*wx.w + gyb*wy.w;
      float4 w[8];
      #pragma unroll
      for (int j=0;j<8;++j) w[j] = *(const float4*)(Ws + j*32 + dq*4);
      #pragma unroll
      for (int c=0;c<32;++c){
        float4 wc = w[c&7];
        if (c < 24) w[c&7] = *(const float4*)(Ws + (c+8)*32 + dq*4);
        aa.x += xa[c]*wc.x; aa.y += xa[c]*wc.y; aa.z += xa[c]*wc.z; aa.w += xa[c]*wc.w;
        ab.x += xb[c]*wc.x; ab.y += xb[c]*wc.y; ab.z += xb[c]*wc.z; ab.w += xb[c]*wc.w;
      }
      __builtin_amdgcn_sched_barrier(0);
      ya[dq*4+0]=fsilu(aa.x); ya[dq*4+1]=fsilu(aa.y); ya[dq*4+2]=fsilu(aa.z); ya[dq*4+3]=fsilu(aa.w);
      yb[dq*4+0]=fsilu(ab.x); yb[dq*4+1]=fsilu(ab.y); yb[dq*4+2]=fsilu(ab.z); yb[dq*4+3]=fsilu(ab.w);
    }
    // -------- layer 2 (h overwrites xa/xb; x dead) --------
    #pragma unroll
    for (int dq=0; dq<8; ++dq){
      float4 bb = *(const float4*)(Ws + 2144 + dq*4);
      float4 aa = bb, ab = bb;
      float4 w[8];
      #pragma unroll
      for (int j=0;j<8;++j) w[j] = *(const float4*)(Ws + 1120 + j*32 + dq*4);
      #pragma unroll
      for (int c=0;c<32;++c){
        float4 wc = w[c&7];
        if (c < 24) w[c&7] = *(const float4*)(Ws + 1120 + (c+8)*32 + dq*4);
        aa.x += ya[c]*wc.x; aa.y += ya[c]*wc.y; aa.z += ya[c]*wc.z; aa.w += ya[c]*wc.w;
        ab.x += yb[c]*wc.x; ab.y += yb[c]*wc.y; ab.z += yb[c]*wc.z; ab.w += yb[c]*wc.w;
      }
      __builtin_amdgcn_sched_barrier(0);
      xa[dq*4+0]=fsilu(aa.x); xa[dq*4+1]=fsilu(aa.y); xa[dq*4+2]=fsilu(aa.z); xa[dq*4+3]=fsilu(aa.w);
      xb[dq*4+0]=fsilu(ab.x); xb[dq*4+1]=fsilu(ab.y); xb[dq*4+2]=fsilu(ab.z); xb[dq*4+3]=fsilu(ab.w);
    }
    // -------- layer 3 + argmax --------
    #pragma unroll
    for (int kq=0; kq<5; ++kq){
      float4 aa = *(const float4*)(B3p + kq*4);
      float4 ab = aa;
      float4 w[8];
      #pragma unroll
      for (int j=0;j<8;++j) w[j] = *(const float4*)(W3p + j*20 + kq*4);
      #pragma unroll
      for (int c=0;c<32;++c){
        float4 wc = w[c&7];
        if (c < 24) w[c&7] = *(const float4*)(W3p + (c+8)*20 + kq*4);
        aa.x += xa[c]*wc.x; aa.y += xa[c]*wc.y; aa.z += xa[c]*wc.z; aa.w += xa[c]*wc.w;
        ab.x += xb[c]*wc.x; ab.y += xb[c]*wc.y; ab.z += xb[c]*wc.z; ab.w += xb[c]*wc.w;
      }
      __builtin_amdgcn_sched_barrier(0);
      int k0 = kq*4;
      if (k0+0 < 17){ if (aa.x > bestv[k0+0]){ bestv[k0+0]=aa.x; besti[k0+0]=pa; }
                      if (ab.x > bestv[k0+0]){ bestv[k0+0]=ab.x; besti[k0+0]=pb; } }
      if (k0+1 < 17){ if (aa.y > bestv[k0+1]){ bestv[k0+1]=aa.y; besti[k0+1]=pa; }
                      if (ab.y > bestv[k0+1]){ bestv[k0+1]=ab.y; besti[k0+1]=pb; } }
      if (k0+2 < 17){ if (aa.z > bestv[k0+2]){ bestv[k0+2]=aa.z; besti[k0+2]=pa; }
                      if (ab.z > bestv[k0+2]){ bestv[k0+2]=ab.z; besti[k0+2]=pb; } }
      if (k0+3 < 17){ if (aa.w > bestv[k0+3]){ bestv[k0+3]=aa.w; besti[k0+3]=pa; }
                      if (ab.w > bestv[k0+3]){ bestv[k0+3]=ab.w; besti[k0+3]=pb; } }
    }
  }
  // wave-level reduce (no barriers), then one LDS pass over 4 wave leaders
  __shared__ float rv[4][17];
  __shared__ int   ri[4][17];
  int lane = t & 63, wv = t >> 6;
  #pragma unroll
  for (int k=0;k<17;++k){
    float v = bestv[k]; int ix = besti[k];
    #pragma unroll
    for (int o=32;o>0;o>>=1){
      float v2 = __shfl_xor(v,o); int i2 = __shfl_xor(ix,o);
      if (v2 > v || (v2 == v && i2 < ix)){ v=v2; ix=i2; }
    }
    if (lane==0){ rv[wv][k]=v; ri[wv][k]=ix; }
  }
  __syncthreads();
  if (t < 17){
    float v = rv[0][t]; int ix = ri[0][t];
    #pragma unroll
    for (int w2=1;w2<4;++w2){
      float v2 = rv[w2][t]; int i2 = ri[w2][t];
      if (v2 > v || (v2 == v && i2 < ix)){ v=v2; ix=i2; }
    }
    kp[((size_t)inst*17+t)*2+0] = ((ix & 63)+0.5f)*8.f;
    kp[((size_t)inst*17+t)*2+1] = ((ix >> 6)+0.5f)*8.f;
  }
}

extern "C" void kernel_launch(void* const* d_in, const int* in_sizes, int n_in,
                              void* d_out, int out_size, void* d_ws, size_t ws_size,
                              hipStream_t stream){
  (void)in_sizes; (void)n_in; (void)out_size; (void)ws_size;
  const float* x3      = (const float*)d_in[1];
  const float* x5      = (const float*)d_in[2];
  const float* lat_w   = (const float*)d_in[3];
  const float* lat_b   = (const float*)d_in[4];
  const float* ml_w    = (const float*)d_in[5];
  const float* ml_b    = (const float*)d_in[6];
  const float* mh_w    = (const float*)d_in[7];
  const float* mh_b    = (const float*)d_in[8];
  const float* loc_w   = (const float*)d_in[9];
  const float* loc_b   = (const float*)d_in[10];
  const float* loc_g   = (const float*)d_in[11];
  const float* loc_bt  = (const float*)d_in[12];
  const float* loc_wo  = (const float*)d_in[13];
  const float* loc_bo  = (const float*)d_in[14];
  const float* pre_w   = (const float*)d_in[15];
  const float* pre_b   = (const float*)d_in[16];
  const float* pre_g   = (const float*)d_in[17];
  const float* pre_bt  = (const float*)d_in[18];
  const float* pre_wo  = (const float*)d_in[19];
  const float* pre_bo  = (const float*)d_in[20];
  const float* ker_w   = (const float*)d_in[21];
  const float* ker_b   = (const float*)d_in[22];
  const float* ker_g   = (const float*)d_in[23];
  const float* ker_bt  = (const float*)d_in[24];
  const float* ker_wo  = (const float*)d_in[25];
  const float* ker_bo  = (const float*)d_in[26];

  float* ws = (float*)d_ws;
  float* latwT     = ws;                  // 131072
  float* mlwT      = ws + 131072;         // 65536
  float* feats     = ws + 196608;         // 262144
  float* loc_logit = ws + 720896;         // 1024
  int*   srcrow    = (int*)(ws + 721920); // 512
  float* moff      = ws + 722432;         // 1024
  float* ker_h     = ws + 723456;         // 102400
  float* dwb       = ws + 928256;         // 400*2752 = 1100800
  float* mfl       = ws + 2029056;        // 4194304
  float* partialb  = ws + 6223360;        // 2097152
  float* mfb       = ws + 8320512;        // 524288   (end 8844800 floats ~35.4MB)

  float* out          = (float*)d_out;
  float* out_ninst    = out;
  float* out_scores   = out + 4;
  float* out_presence = out + 404;
  float* out_kp       = out + 7204;

  transpose2_k<<<768, 256, 0, stream>>>(lat_w, latwT, ml_w, mlwT);
  lat_mask_k<<<512, 256, 0, stream>>>(x5, latwT, lat_b, feats, x3, mlwT, ml_b, mfl);
  loc_conv_k<<<320, 256, 0, stream>>>(feats, loc_w, loc_b, loc_g, loc_bt, loc_wo, loc_bo, loc_logit,
                                      mfl, mh_w, partialb);
  topk_epi_k<<<2052, 256, 0, stream>>>(loc_logit, out_scores, out_ninst, srcrow, moff,
                                       partialb, mh_b, mfb);
  mlp_duo_k<<<50, 256, 0, stream>>>(feats, srcrow,
                                    ker_w, ker_b, ker_g, ker_bt, ker_h,
                                    pre_w, pre_b, pre_g, pre_bt, pre_wo, pre_bo, out_presence);
  linear_out_k<<<275, 256, 0, stream>>>(ker_h, ker_wo, ker_bo, dwb, 2737, DWS, 0, 11);
  dyn_k<<<400, 256, 0, stream>>>(mfb, dwb, moff, out_kp);
}

// Round 14
// 826.368 us; speedup vs baseline: 1.4341x; 1.0802x over previous
//
#include <hip/hip_runtime.h>

#define NCH 256
#define DWS 2752   // padded per-instance dynamic-weight stride (64B aligned)

static __device__ __forceinline__ float fsig(float x){ return __builtin_amdgcn_rcpf(1.f + __expf(-x)); }
static __device__ __forceinline__ float fsilu(float x){ return x * __builtin_amdgcn_rcpf(1.f + __expf(-x)); }

// ---------------- fused weight transposes (lat 256x512, ml 256x256) -------
__global__ void transpose2_k(const float* __restrict__ lat_w, float* __restrict__ latwT,
                             const float* __restrict__ ml_w,  float* __restrict__ mlwT){
  int i = blockIdx.x*256 + threadIdx.x;
  if (i < 131072){ int r = i >> 9, c = i & 511; latwT[c*256 + r] = lat_w[i]; }
  else { int j = i - 131072; int r = j >> 8, c = j & 255; mlwT[c*256 + r] = ml_w[j]; }
}

// ---------------- 4-layer MLP core (Linear->LN->SiLU x4), result in acc ----
// final activations also left in xs[wv*4+rr][*] (each wave owns its 4 rows)
__device__ __forceinline__ void mlp_core(const float* __restrict__ X, const int* __restrict__ srcrow,
                             const float* __restrict__ W, const float* __restrict__ B,
                             const float* __restrict__ G, const float* __restrict__ Bt,
                             int row0, float xs[16][NCH], float acc[4][4]){
  int t = threadIdx.x;
  int wv = t >> 6, lane = t & 63;
  for (int rr=0;rr<4;++rr){
    int row = row0+rr;
    int src = srcrow ? srcrow[row] : row;
    #pragma unroll
    for (int q=0;q<4;++q) xs[wv*4+rr][q*64+lane] = X[(size_t)src*NCH + q*64+lane];
  }
  for (int l=0;l<4;++l){
    const float* Wl = W + l*NCH*NCH;
    float4 bb = *(const float4*)(B + l*NCH + lane*4);
    #pragma unroll
    for (int rr=0;rr<4;++rr){ acc[rr][0]=bb.x; acc[rr][1]=bb.y; acc[rr][2]=bb.z; acc[rr][3]=bb.w; }
    for (int c=0;c<NCH;++c){
      float4 w4 = *(const float4*)(Wl + c*NCH + lane*4);
      #pragma unroll
      for (int rr=0;rr<4;++rr){
        float xv = xs[wv*4+rr][c];
        acc[rr][0] += xv*w4.x; acc[rr][1] += xv*w4.y; acc[rr][2] += xv*w4.z; acc[rr][3] += xv*w4.w;
      }
    }
    float4 gg = *(const float4*)(G  + l*NCH + lane*4);
    float4 bt = *(const float4*)(Bt + l*NCH + lane*4);
    #pragma unroll
    for (int rr=0;rr<4;++rr){
      float s  = acc[rr][0]+acc[rr][1]+acc[rr][2]+acc[rr][3];
      float s2 = acc[rr][0]*acc[rr][0]+acc[rr][1]*acc[rr][1]+acc[rr][2]*acc[rr][2]+acc[rr][3]*acc[rr][3];
      #pragma unroll
      for (int o=32;o>0;o>>=1){ s += __shfl_xor(s,o); s2 += __shfl_xor(s2,o); }
      float m = s*(1.f/256.f);
      float rstd = __builtin_amdgcn_rsqf(s2*(1.f/256.f) - m*m + 1e-5f);
      float z0 = fsilu((acc[rr][0]-m)*rstd*gg.x + bt.x);
      float z1 = fsilu((acc[rr][1]-m)*rstd*gg.y + bt.y);
      float z2 = fsilu((acc[rr][2]-m)*rstd*gg.z + bt.z);
      float z3 = fsilu((acc[rr][3]-m)*rstd*gg.w + bt.w);
      acc[rr][0]=z0; acc[rr][1]=z1; acc[rr][2]=z2; acc[rr][3]=z3;
      *(float4*)(&xs[wv*4+rr][lane*4]) = make_float4(z0,z1,z2,z3);
    }
  }
}

// ---------------- merged L1: lat5 (blocks 0..255) | masklat (256..511) -----
__global__ void __launch_bounds__(256) lat_mask_k(
    const float* __restrict__ x5, const float* __restrict__ latwT,
    const float* __restrict__ lat_b, float* __restrict__ feats,
    const float* __restrict__ x3, const float* __restrict__ mlwT,
    const float* __restrict__ ml_b, float* __restrict__ mfl){
  __shared__ float s5[4][512];
  __shared__ float s3[16][64];
  int t = threadIdx.x;
  if (blockIdx.x < 256){
    int bid = blockIdx.x;
    int b  = bid >> 6;
    int p0 = (bid & 63) * 4;
    int tl = t & 63, pg = t >> 6;
    for (int s=t; s<2048; s+=256){ int c=s>>2, px=s&3; s5[px][c] = x5[(b*512+c)*256 + p0+px]; }
    __syncthreads();
    float a0=0.f,a1=0.f,a2=0.f,a3=0.f;
    const float* xrow = s5[pg];
    for (int c=0;c<512;++c){
      float xv = xrow[c];
      float4 wv = *(const float4*)(latwT + c*256 + tl*4);
      a0 += xv*wv.x; a1 += xv*wv.y; a2 += xv*wv.z; a3 += xv*wv.w;
    }
    float4 bb = *(const float4*)(lat_b + tl*4);
    float4 o; o.x=a0+bb.x; o.y=a1+bb.y; o.z=a2+bb.z; o.w=a3+bb.w;
    *(float4*)(feats + (size_t)(b*256 + p0+pg)*256 + tl*4) = o;
  } else {
    int bid = blockIdx.x - 256;
    int b  = bid >> 6;
    int p0 = (bid & 63) * 64;
    int tl = t & 63, pg = t >> 6;
    float acc[4][16];
    #pragma unroll
    for (int dd=0;dd<4;++dd)
      #pragma unroll
      for (int r=0;r<16;++r) acc[dd][r]=0.f;
    for (int c0=0;c0<256;c0+=16){
      __syncthreads();
      for (int s=t; s<1024; s+=256){ int cc=s>>6, pp=s&63; s3[cc][pp] = x3[(size_t)(b*256 + c0+cc)*4096 + p0+pp]; }
      __syncthreads();
      #pragma unroll
      for (int cc=0;cc<16;++cc){
        float4 w4 = *(const float4*)(mlwT + (c0+cc)*256 + tl*4);
        #pragma unroll
        for (int r4=0;r4<4;++r4){
          float4 xv = *(const float4*)(&s3[cc][pg*16 + r4*4]);
          acc[0][r4*4+0]+=xv.x*w4.x; acc[0][r4*4+1]+=xv.y*w4.x; acc[0][r4*4+2]+=xv.z*w4.x; acc[0][r4*4+3]+=xv.w*w4.x;
          acc[1][r4*4+0]+=xv.x*w4.y; acc[1][r4*4+1]+=xv.y*w4.y; acc[1][r4*4+2]+=xv.z*w4.y; acc[1][r4*4+3]+=xv.w*w4.y;
          acc[2][r4*4+0]+=xv.x*w4.z; acc[2][r4*4+1]+=xv.y*w4.z; acc[2][r4*4+2]+=xv.z*w4.z; acc[2][r4*4+3]+=xv.w*w4.z;
          acc[3][r4*4+0]+=xv.x*w4.w; acc[3][r4*4+1]+=xv.y*w4.w; acc[3][r4*4+2]+=xv.z*w4.w; acc[3][r4*4+3]+=xv.w*w4.w;
        }
      }
    }
    float4 bb = *(const float4*)(ml_b + tl*4);
    float bias[4] = {bb.x, bb.y, bb.z, bb.w};
    #pragma unroll
    for (int dd=0;dd<4;++dd){
      float* base = mfl + (size_t)(b*256 + tl*4+dd)*4096 + p0 + pg*16;
      #pragma unroll
      for (int r4=0;r4<4;++r4)
        *(float4*)(base + r4*4) = make_float4(acc[dd][r4*4+0]+bias[dd], acc[dd][r4*4+1]+bias[dd],
                                              acc[dd][r4*4+2]+bias[dd], acc[dd][r4*4+3]+bias[dd]);
    }
  }
}

// ---------------- merged L2: mlp_loc (0..63) | conv3x3 (64..319) -----------
__global__ void __launch_bounds__(256) loc_conv_k(
    const float* __restrict__ feats,
    const float* __restrict__ loc_w, const float* __restrict__ loc_b,
    const float* __restrict__ loc_g, const float* __restrict__ loc_bt,
    const float* __restrict__ loc_wo, const float* __restrict__ loc_bo,
    float* __restrict__ logits,
    const float* __restrict__ mfl, const float* __restrict__ mh_w,
    float* __restrict__ partial){
  __shared__ float xs[16][NCH];
  __shared__ float hal[18*18];
  __shared__ float wl[288];
  int t = threadIdx.x;
  if (blockIdx.x < 64){
    float acc[4][4];
    int wv = t>>6, lane = t&63;
    int row0 = blockIdx.x*16 + wv*4;
    mlp_core(feats, nullptr, loc_w, loc_b, loc_g, loc_bt, row0, xs, acc);
    float4 wo = *(const float4*)(loc_wo + lane*4);
    float b0 = loc_bo[0];
    #pragma unroll
    for (int rr=0;rr<4;++rr){
      float p = acc[rr][0]*wo.x + acc[rr][1]*wo.y + acc[rr][2]*wo.z + acc[rr][3]*wo.w;
      #pragma unroll
      for (int o=32;o>0;o>>=1) p += __shfl_xor(p,o);
      if (lane==0) logits[row0+rr] = p + b0;
    }
  } else {
    int bid = blockIdx.x - 64;
    int g = bid & 3, tile = (bid>>2) & 15, b = bid >> 6;
    int ty0 = (tile>>2)*16, tx0 = (tile&3)*16;
    int dg = t >> 6;
    int pb = t & 63; int pby = pb >> 3, pbx = pb & 7;
    int py = pby*2, px = pbx*2;
    float acc[8][4];
    #pragma unroll
    for (int dd=0;dd<8;++dd){ acc[dd][0]=0.f; acc[dd][1]=0.f; acc[dd][2]=0.f; acc[dd][3]=0.f; }
    for (int c = g*64; c < (g+1)*64; ++c){
      __syncthreads();
      for (int s=t; s<324; s+=256){
        int hy = s/18, hx = s - hy*18;
        int gy = ty0+hy-1, gx = tx0+hx-1;
        float vv = 0.f;
        if ((unsigned)gy < 64u && (unsigned)gx < 64u) vv = mfl[(size_t)(b*256+c)*4096 + gy*64+gx];
        hal[s] = vv;
      }
      for (int s=t; s<288; s+=256){ int d=s/9, tap=s-d*9; wl[s] = mh_w[(size_t)(d*256+c)*9 + tap]; }
      __syncthreads();
      float nb[4][4];
      #pragma unroll
      for (int i=0;i<4;++i)
        #pragma unroll
        for (int j=0;j<4;++j) nb[i][j] = hal[(py+i)*18 + (px+j)];
      #pragma unroll
      for (int dd=0;dd<8;++dd){
        int d = dg*8+dd;
        #pragma unroll
        for (int ky=0;ky<3;++ky)
          #pragma unroll
          for (int kx=0;kx<3;++kx){
            float wv = wl[d*9 + ky*3+kx];
            acc[dd][0] += nb[ky+0][kx+0]*wv;
            acc[dd][1] += nb[ky+0][kx+1]*wv;
            acc[dd][2] += nb[ky+1][kx+0]*wv;
            acc[dd][3] += nb[ky+1][kx+1]*wv;
          }
      }
    }
    #pragma unroll
    for (int dd=0;dd<8;++dd){
      int d = dg*8+dd;
      float* pp = partial + ((size_t)(g*4+b)*32 + d)*4096;
      pp[(ty0+py  )*64 + tx0+px  ] = acc[dd][0];
      pp[(ty0+py  )*64 + tx0+px+1] = acc[dd][1];
      pp[(ty0+py+1)*64 + tx0+px  ] = acc[dd][2];
      pp[(ty0+py+1)*64 + tx0+px+1] = acc[dd][3];
    }
  }
}

// ---------------- merged L3: topk (0..3) | convepi (4..2051) ---------------
__global__ void topk_epi_k(const float* __restrict__ logits, float* __restrict__ out_scores,
                           float* __restrict__ out_ninst, int* __restrict__ srcrow,
                           float* __restrict__ mask_off,
                           const float* __restrict__ partial, const float* __restrict__ mh_b,
                           float* __restrict__ mf){
  __shared__ float v[256];
  __shared__ int cnt;
  int t = threadIdx.x;
  if (blockIdx.x < 4){
    int b = blockIdx.x;
    v[t] = logits[b*256+t];
    if (t==0) cnt=0;
    __syncthreads();
    float mv = v[t];
    int rank = 0;
    for (int j=0;j<256;++j){
      float u = v[j];
      rank += (u > mv) || (u == mv && j < t);
    }
    if (rank < 100){
      out_scores[b*100 + rank] = fsig(mv);
      srcrow[b*100 + rank] = b*256 + t;
      mask_off[(b*100+rank)*2+0] = ((t & 15) + 0.5f)*(1.f/16.f);
      mask_off[(b*100+rank)*2+1] = ((t >> 4) + 0.5f)*(1.f/16.f);
      if (mv > 0.f) atomicAdd(&cnt, 1);
    }
    __syncthreads();
    if (t==0) out_ninst[b] = (float)cnt;
  } else {
    int i = (blockIdx.x-4)*256 + t;      // 4*32*4096
    int p = i & 4095; int d = (i>>12) & 31; int b = i >> 17;
    float s = mh_b[d];
    #pragma unroll
    for (int g=0; g<4; ++g) s += partial[((size_t)(g*4+b)*32 + d)*4096 + p];
    mf[i] = fsilu(s);
  }
}

// ---------------- heads: blocks 0..274 = ker MLP (recomputed) + 2737 head;
//                  blocks 275..299 = pre MLP + 17-wide presence head --------
__global__ void __launch_bounds__(256) heads_k(const float* __restrict__ feats, const int* __restrict__ srcrow,
                             const float* __restrict__ ker_w, const float* __restrict__ ker_b,
                             const float* __restrict__ ker_g, const float* __restrict__ ker_bt,
                             const float* __restrict__ ker_wo, const float* __restrict__ ker_bo,
                             float* __restrict__ dwb,
                             const float* __restrict__ pre_w, const float* __restrict__ pre_b,
                             const float* __restrict__ pre_g, const float* __restrict__ pre_bt,
                             const float* __restrict__ preWo, const float* __restrict__ preBo,
                             float* __restrict__ presence){
  __shared__ float xs[16][NCH];
  float acc[4][4];
  int t = threadIdx.x, wv = t>>6, lane = t&63;
  int bid = blockIdx.x;
  if (bid < 275){
    int rt = bid / 11, jtile = bid - rt*11;
    // row0 must include wv*4: mlp_core uses row0+rr for srcrow but stores to
    // xs[wv*4+rr] (r13 bug: passing rt*16 gave every wave rows 0..3's data).
    mlp_core(feats, srcrow, ker_w, ker_b, ker_g, ker_bt, rt*16 + wv*4, xs, acc);
    int j0 = jtile*256;
    int jbase = j0 + lane*4;
    int jok[4]; float bo[4];
    #pragma unroll
    for (int jj=0;jj<4;++jj){ jok[jj] = (jbase+jj < 2737); bo[jj] = jok[jj] ? ker_bo[jbase+jj] : 0.f; }
    float o[4][4];
    #pragma unroll
    for (int rr=0;rr<4;++rr){ o[rr][0]=bo[0]; o[rr][1]=bo[1]; o[rr][2]=bo[2]; o[rr][3]=bo[3]; }
    for (int c=0;c<NCH;++c){
      float w0 = jok[0] ? ker_wo[(size_t)c*2737 + jbase+0] : 0.f;
      float w1 = jok[1] ? ker_wo[(size_t)c*2737 + jbase+1] : 0.f;
      float w2 = jok[2] ? ker_wo[(size_t)c*2737 + jbase+2] : 0.f;
      float w3 = jok[3] ? ker_wo[(size_t)c*2737 + jbase+3] : 0.f;
      #pragma unroll
      for (int rr=0;rr<4;++rr){
        float xv = xs[wv*4+rr][c];
        o[rr][0]+=xv*w0; o[rr][1]+=xv*w1; o[rr][2]+=xv*w2; o[rr][3]+=xv*w3;
      }
    }
    #pragma unroll
    for (int rr=0;rr<4;++rr)
      #pragma unroll
      for (int jj=0;jj<4;++jj)
        if (jok[jj]) dwb[(size_t)(rt*16+wv*4+rr)*DWS + jbase+jj] = o[rr][jj];
  } else {
    int row0 = (bid-275)*16 + wv*4;
    mlp_core(feats, srcrow, pre_w, pre_b, pre_g, pre_bt, row0, xs, acc);
    int c0 = lane*4;
    #pragma unroll
    for (int rr=0;rr<4;++rr){
      for (int k=0;k<17;++k){
        float p = acc[rr][0]*preWo[(c0+0)*17+k] + acc[rr][1]*preWo[(c0+1)*17+k]
                + acc[rr][2]*preWo[(c0+2)*17+k] + acc[rr][3]*preWo[(c0+3)*17+k];
        #pragma unroll
        for (int o=32;o>0;o>>=1) p += __shfl_xor(p,o);
        if (lane==0) presence[(size_t)(row0+rr)*17 + k] = fsig(p + preBo[k]);
      }
    }
  }
}

// ---------------- dynamic per-instance convs + argmax ----------------------
// 2 px/thread; weights via LDS broadcast b128. 4-deep rotating prefetch
// (r10-measured best: 327us, VGPR 240, no spill; 8-deep hit the 256 cap
// and spilled — r12). sched_barrier(0) only at group boundaries.
__global__ void __launch_bounds__(256,1) dyn_k(const float* __restrict__ mf, const float* __restrict__ dw,
                      const float* __restrict__ mask_off, float* __restrict__ kp){
  int inst = blockIdx.x;
  int b = inst / 100;
  int t = threadIdx.x;
  __shared__ __align__(16) float Ws[2176];   // w1[34][32] | b1[32] | w2[32][32] | b2[32]
  __shared__ __align__(16) float W3p[640];   // [c(32)][k(20)] padded
  __shared__ __align__(16) float B3p[20];
  __shared__ float offsh[2];
  const float* src = dw + (size_t)inst*DWS;
  for (int s=t; s<2176; s+=256) Ws[s] = src[s];
  for (int s=t; s<640; s+=256){ int c=s/20, k=s-c*20; W3p[s] = (k<17) ? src[2176 + c*17 + k] : 0.f; }
  if (t<20) B3p[t] = (t<17) ? src[2720+t] : 0.f;
  if (t<2) offsh[t] = mask_off[inst*2+t];
  __syncthreads();
  float offx = offsh[0], offy = offsh[1];
  float bestv[17]; int besti[17];
  #pragma unroll
  for (int k=0;k<17;++k){ bestv[k] = -3.4e38f; besti[k]=0; }
  const float* mfb = mf + (size_t)b*32*4096;
  #pragma unroll 1
  for (int chk=0; chk<8; ++chk){
    int pa = chk*512 + t;
    int pb = pa + 256;
    float xa[32], xb[32];
    #pragma unroll
    for (int c=0;c<32;++c){
      const float* mp = mfb + c*4096;
      xa[c] = mp[pa]; xb[c] = mp[pb];
    }
    float gxa = ((pa & 63) + 0.5f)*(1.f/64.f) - offx;
    float gya = ((pa >> 6) + 0.5f)*(1.f/64.f) - offy;
    float gxb = ((pb & 63) + 0.5f)*(1.f/64.f) - offx;
    float gyb = ((pb >> 6) + 0.5f)*(1.f/64.f) - offy;
    float ya[32], yb[32];
    // -------- layer 1 --------
    #pragma unroll
    for (int dq=0; dq<8; ++dq){
      float4 bb = *(const float4*)(Ws + 1088 + dq*4);
      float4 wx = *(const float4*)(Ws + 32*32 + dq*4);
      float4 wy = *(const float4*)(Ws + 33*32 + dq*4);
      float4 aa, ab;
      aa.x = bb.x + gxa*wx.x + gya*wy.x; aa.y = bb.y + gxa*wx.y + gya*wy.y;
      aa.z = bb.z + gxa*wx.z + gya*wy.z; aa.w = bb.w + gxa*wx.w + gya*wy.w;
      ab.x = bb.x + gxb*wx.x + gyb*wy.x; ab.y = bb.y + gxb*wx.y + gyb*wy.y;
      ab.z = bb.z + gxb*wx.z + gyb*wy.z; ab.w = bb.w + gxb*wx.w + gyb*wy.w;
      float4 w[4];
      #pragma unroll
      for (int j=0;j<4;++j) w[j] = *(const float4*)(Ws + j*32 + dq*4);
      #pragma unroll
      for (int c=0;c<32;++c){
        float4 wc = w[c&3];
        if (c < 28) w[c&3] = *(const float4*)(Ws + (c+4)*32 + dq*4);
        aa.x += xa[c]*wc.x; aa.y += xa[c]*wc.y; aa.z += xa[c]*wc.z; aa.w += xa[c]*wc.w;
        ab.x += xb[c]*wc.x; ab.y += xb[c]*wc.y; ab.z += xb[c]*wc.z; ab.w += xb[c]*wc.w;
      }
      __builtin_amdgcn_sched_barrier(0);
      ya[dq*4+0]=fsilu(aa.x); ya[dq*4+1]=fsilu(aa.y); ya[dq*4+2]=fsilu(aa.z); ya[dq*4+3]=fsilu(aa.w);
      yb[dq*4+0]=fsilu(ab.x); yb[dq*4+1]=fsilu(ab.y); yb[dq*4+2]=fsilu(ab.z); yb[dq*4+3]=fsilu(ab.w);
    }
    // -------- layer 2 (h overwrites xa/xb; x dead) --------
    #pragma unroll
    for (int dq=0; dq<8; ++dq){
      float4 bb = *(const float4*)(Ws + 2144 + dq*4);
      float4 aa = bb, ab = bb;
      float4 w[4];
      #pragma unroll
      for (int j=0;j<4;++j) w[j] = *(const float4*)(Ws + 1120 + j*32 + dq*4);
      #pragma unroll
      for (int c=0;c<32;++c){
        float4 wc = w[c&3];
        if (c < 28) w[c&3] = *(const float4*)(Ws + 1120 + (c+4)*32 + dq*4);
        aa.x += ya[c]*wc.x; aa.y += ya[c]*wc.y; aa.z += ya[c]*wc.z; aa.w += ya[c]*wc.w;
        ab.x += yb[c]*wc.x; ab.y += yb[c]*wc.y; ab.z += yb[c]*wc.z; ab.w += yb[c]*wc.w;
      }
      __builtin_amdgcn_sched_barrier(0);
      xa[dq*4+0]=fsilu(aa.x); xa[dq*4+1]=fsilu(aa.y); xa[dq*4+2]=fsilu(aa.z); xa[dq*4+3]=fsilu(aa.w);
      xb[dq*4+0]=fsilu(ab.x); xb[dq*4+1]=fsilu(ab.y); xb[dq*4+2]=fsilu(ab.z); xb[dq*4+3]=fsilu(ab.w);
    }
    // -------- layer 3 + argmax --------
    #pragma unroll
    for (int kq=0; kq<5; ++kq){
      float4 aa = *(const float4*)(B3p + kq*4);
      float4 ab = aa;
      float4 w[4];
      #pragma unroll
      for (int j=0;j<4;++j) w[j] = *(const float4*)(W3p + j*20 + kq*4);
      #pragma unroll
      for (int c=0;c<32;++c){
        float4 wc = w[c&3];
        if (c < 28) w[c&3] = *(const float4*)(W3p + (c+4)*20 + kq*4);
        aa.x += xa[c]*wc.x; aa.y += xa[c]*wc.y; aa.z += xa[c]*wc.z; aa.w += xa[c]*wc.w;
        ab.x += xb[c]*wc.x; ab.y += xb[c]*wc.y; ab.z += xb[c]*wc.z; ab.w += xb[c]*wc.w;
      }
      __builtin_amdgcn_sched_barrier(0);
      int k0 = kq*4;
      if (k0+0 < 17){ if (aa.x > bestv[k0+0]){ bestv[k0+0]=aa.x; besti[k0+0]=pa; }
                      if (ab.x > bestv[k0+0]){ bestv[k0+0]=ab.x; besti[k0+0]=pb; } }
      if (k0+1 < 17){ if (aa.y > bestv[k0+1]){ bestv[k0+1]=aa.y; besti[k0+1]=pa; }
                      if (ab.y > bestv[k0+1]){ bestv[k0+1]=ab.y; besti[k0+1]=pb; } }
      if (k0+2 < 17){ if (aa.z > bestv[k0+2]){ bestv[k0+2]=aa.z; besti[k0+2]=pa; }
                      if (ab.z > bestv[k0+2]){ bestv[k0+2]=ab.z; besti[k0+2]=pb; } }
      if (k0+3 < 17){ if (aa.w > bestv[k0+3]){ bestv[k0+3]=aa.w; besti[k0+3]=pa; }
                      if (ab.w > bestv[k0+3]){ bestv[k0+3]=ab.w; besti[k0+3]=pb; } }
    }
  }
  // wave-level reduce (no barriers), then one LDS pass over 4 wave leaders
  __shared__ float rv[4][17];
  __shared__ int   ri[4][17];
  int lane = t & 63, wv = t >> 6;
  #pragma unroll
  for (int k=0;k<17;++k){
    float v = bestv[k]; int ix = besti[k];
    #pragma unroll
    for (int o=32;o>0;o>>=1){
      float v2 = __shfl_xor(v,o); int i2 = __shfl_xor(ix,o);
      if (v2 > v || (v2 == v && i2 < ix)){ v=v2; ix=i2; }
    }
    if (lane==0){ rv[wv][k]=v; ri[wv][k]=ix; }
  }
  __syncthreads();
  if (t < 17){
    float v = rv[0][t]; int ix = ri[0][t];
    #pragma unroll
    for (int w2=1;w2<4;++w2){
      float v2 = rv[w2][t]; int i2 = ri[w2][t];
      if (v2 > v || (v2 == v && i2 < ix)){ v=v2; ix=i2; }
    }
    kp[((size_t)inst*17+t)*2+0] = ((ix & 63)+0.5f)*8.f;
    kp[((size_t)inst*17+t)*2+1] = ((ix >> 6)+0.5f)*8.f;
  }
}

extern "C" void kernel_launch(void* const* d_in, const int* in_sizes, int n_in,
                              void* d_out, int out_size, void* d_ws, size_t ws_size,
                              hipStream_t stream){
  (void)in_sizes; (void)n_in; (void)out_size; (void)ws_size;
  const float* x3      = (const float*)d_in[1];
  const float* x5      = (const float*)d_in[2];
  const float* lat_w   = (const float*)d_in[3];
  const float* lat_b   = (const float*)d_in[4];
  const float* ml_w    = (const float*)d_in[5];
  const float* ml_b    = (const float*)d_in[6];
  const float* mh_w    = (const float*)d_in[7];
  const float* mh_b    = (const float*)d_in[8];
  const float* loc_w   = (const float*)d_in[9];
  const float* loc_b   = (const float*)d_in[10];
  const float* loc_g   = (const float*)d_in[11];
  const float* loc_bt  = (const float*)d_in[12];
  const float* loc_wo  = (const float*)d_in[13];
  const float* loc_bo  = (const float*)d_in[14];
  const float* pre_w   = (const float*)d_in[15];
  const float* pre_b   = (const float*)d_in[16];
  const float* pre_g   = (const float*)d_in[17];
  const float* pre_bt  = (const float*)d_in[18];
  const float* pre_wo  = (const float*)d_in[19];
  const float* pre_bo  = (const float*)d_in[20];
  const float* ker_w   = (const float*)d_in[21];
  const float* ker_b   = (const float*)d_in[22];
  const float* ker_g   = (const float*)d_in[23];
  const float* ker_bt  = (const float*)d_in[24];
  const float* ker_wo  = (const float*)d_in[25];
  const float* ker_bo  = (const float*)d_in[26];

  float* ws = (float*)d_ws;
  float* latwT     = ws;                  // 131072
  float* mlwT      = ws + 131072;         // 65536
  float* feats     = ws + 196608;         // 262144
  float* loc_logit = ws + 720896;         // 1024
  int*   srcrow    = (int*)(ws + 721920); // 512
  float* moff      = ws + 722432;         // 1024
  float* dwb       = ws + 928256;         // 400*2752 = 1100800
  float* mfl       = ws + 2029056;        // 4194304
  float* partialb  = ws + 6223360;        // 2097152
  float* mfb       = ws + 8320512;        // 524288   (end 8844800 floats ~35.4MB)

  float* out          = (float*)d_out;
  float* out_ninst    = out;
  float* out_scores   = out + 4;
  float* out_presence = out + 404;
  float* out_kp       = out + 7204;

  transpose2_k<<<768, 256, 0, stream>>>(lat_w, latwT, ml_w, mlwT);
  lat_mask_k<<<512, 256, 0, stream>>>(x5, latwT, lat_b, feats, x3, mlwT, ml_b, mfl);
  loc_conv_k<<<320, 256, 0, stream>>>(feats, loc_w, loc_b, loc_g, loc_bt, loc_wo, loc_bo, loc_logit,
                                      mfl, mh_w, partialb);
  topk_epi_k<<<2052, 256, 0, stream>>>(loc_logit, out_scores, out_ninst, srcrow, moff,
                                       partialb, mh_b, mfb);
  heads_k<<<300, 256, 0, stream>>>(feats, srcrow,
                                   ker_w, ker_b, ker_g, ker_bt, ker_wo, ker_bo, dwb,
                                   pre_w, pre_b, pre_g, pre_bt, pre_wo, pre_bo, out_presence);
  dyn_k<<<400, 256, 0, stream>>>(mfb, dwb, moff, out_kp);
}